// Round 8
// baseline (237.390 us; speedup 1.0000x reference)
//
#include <hip/hip_runtime.h>
#include <stdint.h>

// LATENT=128, HIDDEN=2048, N_PARTS=128, K=2048
// outputs: omega(1152,2048) transf(1536,2048) rot(1152,2048) transl(384,2048)

typedef short bf16x8 __attribute__((ext_vector_type(8)));
typedef float f32x4 __attribute__((ext_vector_type(4)));

__device__ __forceinline__ unsigned short f2bf(float f) {
  unsigned int x = __float_as_uint(f);
  unsigned int r = (x + 0x7fffu + ((x >> 16) & 1u)) >> 16;
  return (unsigned short)r;
}

__device__ __forceinline__ void gld_lds16(const void* g, void* l) {
  __builtin_amdgcn_global_load_lds(
      (__attribute__((address_space(1))) void*)(g),
      (__attribute__((address_space(3))) void*)(l),
      16, 0, 0);
}

// LDS byte-offset of a generic pointer into __shared__ (AS3 ptrs are 32-bit).
__device__ __forceinline__ unsigned lds_addr(const void* p) {
  return (unsigned)(uintptr_t)(__attribute__((address_space(3))) const void*)p;
}

// Opaque ds_read_b128: no compiler alias tracking vs LDS-DMA, so no
// auto-inserted vmcnt(0) drains. Consumers MUST be fenced with
// lgkmcnt(0)+sched_barrier(0) (rule #18) — INCLUDING plain register copies
// of the result (round-7 bug: v_mov of an in-flight ds_read dest = garbage).
__device__ __forceinline__ bf16x8 ds_read128(unsigned a) {
  bf16x8 r;
  asm volatile("ds_read_b128 %0, %1" : "=v"(r) : "v"(a));
  return r;
}

#define ASM_BAR asm volatile("s_barrier" ::: "memory")
#define LGKM0   asm volatile("s_waitcnt lgkmcnt(0)" ::: "memory")
#define VMCNT0  asm volatile("s_waitcnt vmcnt(0)" ::: "memory")
#define SCHED0  __builtin_amdgcn_sched_barrier(0)

// ---------------------------------------------------------------------------
// Prep: blocks 0..9983 cast all 8 weights fp32->bf16 (8 elems/thread, 16 B
// stores); blocks 9984..10239 transpose+cast x (128x2048) -> Xt (2048x128).
__global__ void prep_k(const float* __restrict__ x,
                       const float* __restrict__ wo0, const float* __restrict__ wo1,
                       const float* __restrict__ wo2, const float* __restrict__ wo3,
                       const float* __restrict__ wt0, const float* __restrict__ wt1,
                       const float* __restrict__ wt2, const float* __restrict__ wt3,
                       unsigned short* __restrict__ dst, unsigned short* __restrict__ xt) {
  __shared__ float tile[32][33];
  const int b = blockIdx.x;
  const int tid = threadIdx.x;
  if (b >= 9984) {
    const int r = b - 9984;
    const int bx = r & 63, by = r >> 6;
    const int tx = tid & 31, ty = tid >> 5;
#pragma unroll
    for (int i = 0; i < 32; i += 8)
      tile[ty + i][tx] = x[(size_t)(by * 32 + ty + i) * 2048 + bx * 32 + tx];
    __syncthreads();
#pragma unroll
    for (int i = 0; i < 32; i += 8)
      xt[(size_t)(bx * 32 + ty + i) * 128 + by * 32 + tx] = f2bf(tile[tx][ty + i]);
    return;
  }
  int idx = (b * 256 + tid) * 8;
  if (idx >= 20447232) return;
  const float* src;
  int off;
  if (idx < 8650752) {
    if (idx < 262144)       { src = wo0; off = idx; }
    else if (idx < 4456448) { src = wo1; off = idx - 262144; }
    else                    { src = wo2; off = idx - 4456448; }
  } else {
    if (idx < 11010048)      { src = wo3; off = idx - 8650752; }
    else if (idx < 11272192) { src = wt0; off = idx - 11010048; }
    else if (idx < 15466496) { src = wt1; off = idx - 11272192; }
    else if (idx < 19660800) { src = wt2; off = idx - 15466496; }
    else                     { src = wt3; off = idx - 19660800; }
  }
  float4 a = *(const float4*)(src + off);
  float4 c = *(const float4*)(src + off + 4);
  uint4 o;
  o.x = (unsigned)f2bf(a.x) | ((unsigned)f2bf(a.y) << 16);
  o.y = (unsigned)f2bf(a.z) | ((unsigned)f2bf(a.w) << 16);
  o.z = (unsigned)f2bf(c.x) | ((unsigned)f2bf(c.y) << 16);
  o.w = (unsigned)f2bf(c.z) | ((unsigned)f2bf(c.w) << 16);
  *(uint4*)(dst + idx) = o;
}

// ---------------------------------------------------------------------------
// Proven 128x128-tile TN GEMM (2-barrier structure) — used for L0.
template <int SWZ>
__global__ __launch_bounds__(256, 2) void gemm_tn(
    const unsigned short* __restrict__ A0, const unsigned short* __restrict__ B0,
    unsigned short* __restrict__ C0, int n0tiles, int ldc0,
    const unsigned short* __restrict__ A1, const unsigned short* __restrict__ B1,
    unsigned short* __restrict__ C1, int ldc1, int K) {
  __shared__ alignas(16) unsigned short Asl[128 * 128];
  __shared__ alignas(16) unsigned short Bsl[128 * 128];

  int mt, yt;
  if (SWZ) {
    int id = blockIdx.x;
    int xcd = id & 7, s = id >> 3;
    mt = ((xcd & 1) << 3) + (s & 7);
    yt = ((xcd >> 1) << 3) + (s >> 3);
  } else {
    mt = blockIdx.x;
    yt = blockIdx.y;
  }

  const unsigned short* A;
  const unsigned short* B;
  unsigned short* C;
  int ldc;
  if (yt < n0tiles) { A = A0; B = B0; C = C0; ldc = ldc0; }
  else { A = A1; B = B1; C = C1; ldc = ldc1; yt -= n0tiles; }

  const unsigned short* Ab = A + (size_t)mt * 128 * K;
  const unsigned short* Bb = B + (size_t)yt * 128 * K;

  const int tid = threadIdx.x;
  const int wave = tid >> 6, lane = tid & 63;
  const int mw = (wave >> 1) * 64, nw = (wave & 1) * 64;
  const int l16 = lane & 15, quad = lane >> 4;

  f32x4 acc[4][4] = {};

  for (int k0 = 0; k0 < K; k0 += 128) {
#pragma unroll
    for (int i = 0; i < 8; ++i) {
      int c = i * 256 + tid;
      int row = c >> 4;
      int l = (c & 15) ^ (row & 15);
      gld_lds16(Ab + (size_t)row * K + k0 + l * 8, &Asl[c * 8]);
      gld_lds16(Bb + (size_t)row * K + k0 + l * 8, &Bsl[c * 8]);
    }
    __syncthreads();

#pragma unroll
    for (int h = 0; h < 4; ++h) {
      bf16x8 af[4], bfr[4];
#pragma unroll
      for (int t = 0; t < 4; ++t) {
        int row = mw + t * 16 + l16;
        int p = (h * 4 + quad) ^ (row & 15);
        af[t] = *(const bf16x8*)&Asl[row * 128 + p * 8];
      }
#pragma unroll
      for (int t = 0; t < 4; ++t) {
        int row = nw + t * 16 + l16;
        int p = (h * 4 + quad) ^ (row & 15);
        bfr[t] = *(const bf16x8*)&Bsl[row * 128 + p * 8];
      }
#pragma unroll
      for (int tm = 0; tm < 4; ++tm)
#pragma unroll
        for (int tn = 0; tn < 4; ++tn)
          acc[tm][tn] = __builtin_amdgcn_mfma_f32_16x16x32_bf16(af[tm], bfr[tn], acc[tm][tn], 0, 0, 0);
    }
    __syncthreads();
  }

  const int mbase = mt * 128 + mw;
  const int nbase = yt * 128 + nw;
#pragma unroll
  for (int tm = 0; tm < 4; ++tm) {
#pragma unroll
    for (int tn = 0; tn < 4; ++tn) {
      int col = nbase + tn * 16 + l16;
      int row0 = mbase + tm * 16 + quad * 4;
#pragma unroll
      for (int r = 0; r < 4; ++r) {
        float v = fmaxf(acc[tm][tn][r], 0.0f);
        C[(size_t)(row0 + r) * ldc + col] = f2bf(v);
      }
    }
  }
}

// ---------------------------------------------------------------------------
// v4: 128x128 tile, BK=64, 4 waves, double-buffered 64 KB LDS -> 2 WGs/CU,
// 512 WGs. Round-3-verified wait protocol (no counted vmcnt):
//   STAGE(next tile) -> 16 asm ds_read_b128(cur) -> lgkmcnt(0)+sched_barrier
//   -> 32-MFMA setprio cluster -> vmcnt(0) -> s_barrier.
__global__ __launch_bounds__(256, 2) void gemm_db128(
    const unsigned short* __restrict__ A0, const unsigned short* __restrict__ B0,
    unsigned short* __restrict__ C0,
    const unsigned short* __restrict__ A1, const unsigned short* __restrict__ B1,
    unsigned short* __restrict__ C1, int K) {
  __shared__ alignas(16) unsigned short SM[2 * 16384];  // slot: A[0,8192) B[8192,16384) shorts

  const int id = blockIdx.x;          // 512 WGs
  const int xcd = id & 7, s = id >> 3;          // s in [0,64)
  const int mt = s & 15;                        // 16 M-tiles of 128 samples
  const int ntt = xcd * 4 + (s >> 4);           // 32 N-tiles of 128; XCD owns 4 -> B L2-resident

  const unsigned short* A;
  const unsigned short* B;
  unsigned short* C;
  int ntl;
  if (ntt < 16) { A = A0; B = B0; C = C0; ntl = ntt; }
  else          { A = A1; B = B1; C = C1; ntl = ntt - 16; }

  const unsigned short* Ab = A + (size_t)mt * 128 * K;
  const unsigned short* Bb = B + (size_t)ntl * 128 * K;

  const int tid = threadIdx.x;
  const int wave = tid >> 6, lane = tid & 63;
  const int mw = (wave >> 1) * 64, nw = (wave & 1) * 64;
  const int l16 = lane & 15, quad = lane >> 4;

  // Staging precompute: 4 A-loads + 4 B-loads per thread per tile.
  const unsigned short* gA[4];
  const unsigned short* gB[4];
  int dAo[4], dBo[4];
#pragma unroll
  for (int i = 0; i < 4; ++i) {
    int c = i * 256 + tid;            // 0..1023: 128 rows x 8 chunks
    int row = c >> 3, pc = c & 7, l = pc ^ (row & 7);
    gA[i] = Ab + (size_t)row * K + l * 8;
    dAo[i] = c * 8;
    gB[i] = Bb + (size_t)row * K + l * 8;
    dBo[i] = 8192 + c * 8;
  }

  // Fragment read byte-offsets within a slot, k-sub phase 0/1.
  unsigned aoff[2][4], boff[2][4];
#pragma unroll
  for (int ph = 0; ph < 2; ++ph)
#pragma unroll
    for (int i = 0; i < 4; ++i) {
      int ra = mw + i * 16 + l16;
      aoff[ph][i] = (unsigned)(ra * 128 + (((ph * 4 + quad) ^ (ra & 7)) * 16));
      int rb = nw + i * 16 + l16;
      boff[ph][i] = (unsigned)(16384 + rb * 128 + (((ph * 4 + quad) ^ (rb & 7)) * 16));
    }
  const unsigned Au = lds_addr(SM);   // slot s at Au + s*32768 bytes

  f32x4 acc[4][4] = {};
  const int NT = K >> 6;              // 32 K-tiles

  auto STAGE = [&](int slot, int k1) {
    const int so = slot * 16384;      // shorts
#pragma unroll
    for (int i = 0; i < 4; ++i) gld_lds16(gA[i] + k1, SM + so + dAo[i]);
#pragma unroll
    for (int i = 0; i < 4; ++i) gld_lds16(gB[i] + k1, SM + so + dBo[i]);
  };

  // Prologue: tile 0 staged and drained.
  STAGE(0, 0);
  VMCNT0;
  ASM_BAR;

  int cur = 0;
  for (int t = 0; t < NT; ++t) {
    int k1 = (t + 1) << 6;
    if (k1 > K - 64) k1 = K - 64;     // last iter: redundant stage into dead slot
    STAGE(cur ^ 1, k1);               // 8 loads; waited at end of THIS iter

    const unsigned base = Au + cur * 32768;
    bf16x8 a0[4], b0[4], a1[4], b1[4];
#pragma unroll
    for (int i = 0; i < 4; ++i) a0[i] = ds_read128(base + aoff[0][i]);
#pragma unroll
    for (int i = 0; i < 4; ++i) b0[i] = ds_read128(base + boff[0][i]);
#pragma unroll
    for (int i = 0; i < 4; ++i) a1[i] = ds_read128(base + aoff[1][i]);
#pragma unroll
    for (int i = 0; i < 4; ++i) b1[i] = ds_read128(base + boff[1][i]);
    LGKM0;
    SCHED0;
    __builtin_amdgcn_s_setprio(1);
#pragma unroll
    for (int tm = 0; tm < 4; ++tm)
#pragma unroll
      for (int tn = 0; tn < 4; ++tn)
        acc[tm][tn] = __builtin_amdgcn_mfma_f32_16x16x32_bf16(a0[tm], b0[tn], acc[tm][tn], 0, 0, 0);
#pragma unroll
    for (int tm = 0; tm < 4; ++tm)
#pragma unroll
      for (int tn = 0; tn < 4; ++tn)
        acc[tm][tn] = __builtin_amdgcn_mfma_f32_16x16x32_bf16(a1[tm], b1[tn], acc[tm][tn], 0, 0, 0);
    __builtin_amdgcn_s_setprio(0);
    SCHED0;

    // ---- tile boundary: next tile landed (own stage), slot cur released ----
    VMCNT0;
    ASM_BAR;
    cur ^= 1;
  }

  const int mbase = mt * 128 + mw;
  const int nbase = ntl * 128 + nw;
#pragma unroll
  for (int tm = 0; tm < 4; ++tm) {
#pragma unroll
    for (int tn = 0; tn < 4; ++tn) {
      int col = nbase + tn * 16 + l16;
      int row0 = mbase + tm * 16 + quad * 4;
#pragma unroll
      for (int r = 0; r < 4; ++r) {
        float v = fmaxf(acc[tm][tn][r], 0.0f);
        C[(size_t)(row0 + r) * 2048 + col] = f2bf(v);
      }
    }
  }
}

// ---------------------------------------------------------------------------
__device__ __forceinline__ void mm3(const float* a, const float* b, float* c) {
#pragma unroll
  for (int r = 0; r < 3; ++r)
#pragma unroll
    for (int cc = 0; cc < 3; ++cc)
      c[r * 3 + cc] = a[r * 3 + 0] * b[0 + cc] + a[r * 3 + 1] * b[3 + cc] + a[r * 3 + 2] * b[6 + cc];
}

__device__ __forceinline__ void expm3(const float* a, float* E) {
  // scaling-and-squaring + order-12 Taylor (scaled ||A||_1 <= 0.25)
  float n1 = 0.f;
#pragma unroll
  for (int c = 0; c < 3; ++c) {
    float s = fabsf(a[c]) + fabsf(a[3 + c]) + fabsf(a[6 + c]);
    n1 = fmaxf(n1, s);
  }
  int s = 0;
  if (n1 > 0.25f) {
    s = (int)ceilf(log2f(n1 * 4.0f));
    if (s < 0) s = 0;
  }
  const float scl = exp2f((float)(-s));
  float As[9];
#pragma unroll
  for (int i = 0; i < 9; ++i) As[i] = a[i] * scl;
  float T[9] = {1, 0, 0, 0, 1, 0, 0, 0, 1};
#pragma unroll
  for (int i = 0; i < 9; ++i) E[i] = T[i];
#pragma unroll
  for (int t = 1; t <= 12; ++t) {
    float Tn[9];
    mm3(T, As, Tn);
    const float inv = 1.0f / (float)t;
#pragma unroll
    for (int i = 0; i < 9; ++i) { T[i] = Tn[i] * inv; E[i] += T[i]; }
  }
  for (int q = 0; q < s; ++q) {
    float Tn[9];
    mm3(E, E, Tn);
#pragma unroll
    for (int i = 0; i < 9; ++i) E[i] = Tn[i];
  }
}

// ---------------------------------------------------------------------------
// Final layer + expm + outputs, UNIFORM grid: 256 WGs (32 mt x 8 yt), exactly
// 1 per CU — fixes the makespan imbalance of the old 352-WG kernel.
// Each WG: 64 samples x 192 dims (144 omega from W9 + 48 transl from W3),
// staging BOTH A panels (Ho, Ht rows of the same samples) + merged B panel.
// BK=64 dbuf, round-3-verified v4 wait protocol. LDS 80 KB -> 1 WG/CU.
// Wave split 2M x 2N: wn=1 subtiles 3..5 are transl dims (A-operand = Ht).
// ROUND-8 FIX: the wn=0 register copies a_t <- a_o now sit AFTER
// LGKM0+sched_barrier — copying an asm ds_read output before its wait reads
// a garbage register (round-7 correctness failure).
__global__ __launch_bounds__(256, 1) void gemm_l3u(
    const unsigned short* __restrict__ Ho, const unsigned short* __restrict__ W9,
    const unsigned short* __restrict__ Ht, const unsigned short* __restrict__ W3,
    float* __restrict__ out) {
  __shared__ alignas(16) unsigned short SM[40960];  // 81920 B: Ao 2x8KB | At 2x8KB | B 2x24KB
  float* Cl = (float*)SM;  // 144 x 68 f32 = 39168 B, aliases slots (post-loop only)

  const int mt = blockIdx.x;   // 32 m-tiles of 64 samples
  const int yt = blockIdx.y;   // 8 tiles: 16 parts (144 omega dims) + 48 transl dims
  const int tid = threadIdx.x;
  const int wave = tid >> 6, lane = tid & 63;
  const int wm = wave >> 1, wn = wave & 1;  // 2M x 2N
  const int l16 = lane & 15, quad = lane >> 4;
  const int mbase = mt * 64;

  float* omega  = out;
  float* transf = out + (size_t)1152 * 2048;
  float* rot    = out + (size_t)(1152 + 1536) * 2048;
  float* transl = out + (size_t)(1152 + 1536 + 1152) * 2048;

  const unsigned short* Ao  = Ho + (size_t)mbase * 2048;
  const unsigned short* At  = Ht + (size_t)mbase * 2048;
  const unsigned short* W9p = W9 + (size_t)yt * 144 * 2048;
  const unsigned short* W3p = W3 + (size_t)yt * 48 * 2048;

  // Staging: Ao/At 512 chunks each (2/thread), B 1536 chunks (6/thread).
  const unsigned short* gAo[2];
  const unsigned short* gAt[2];
  int dA[2];
#pragma unroll
  for (int i = 0; i < 2; ++i) {
    int c = i * 256 + tid, row = c >> 3, pc = c & 7, l = pc ^ (row & 7);
    gAo[i] = Ao + (size_t)row * 2048 + l * 8;
    gAt[i] = At + (size_t)row * 2048 + l * 8;
    dA[i] = c * 8;
  }
  const unsigned short* gB[6];
  int dB[6];
#pragma unroll
  for (int i = 0; i < 6; ++i) {
    int c = i * 256 + tid, row = c >> 3, pc = c & 7, l = pc ^ (row & 7);
    gB[i] = (row < 144 ? W9p + (size_t)row * 2048
                       : W3p + (size_t)(row - 144) * 2048) + l * 8;
    dB[i] = c * 8;
  }

  auto STAGE = [&](int s, int k1) {
    const int ao = s * 4096, at = 8192 + s * 4096, bo = 16384 + s * 12288;  // shorts
#pragma unroll
    for (int i = 0; i < 2; ++i) gld_lds16(gAo[i] + k1, SM + ao + dA[i]);
#pragma unroll
    for (int i = 0; i < 2; ++i) gld_lds16(gAt[i] + k1, SM + at + dA[i]);
#pragma unroll
    for (int i = 0; i < 6; ++i) gld_lds16(gB[i] + k1, SM + bo + dB[i]);
  };

  // Fragment byte-offsets within a slot region.
  unsigned aoff[2][2], boff[2][6];
#pragma unroll
  for (int ph = 0; ph < 2; ++ph) {
#pragma unroll
    for (int tm = 0; tm < 2; ++tm) {
      int ra = wm * 32 + tm * 16 + l16;
      aoff[ph][tm] = (unsigned)(ra * 128 + (((ph * 4 + quad) ^ (ra & 7)) * 16));
    }
#pragma unroll
    for (int tb = 0; tb < 6; ++tb) {
      int rb = (wn * 6 + tb) * 16 + l16;
      boff[ph][tb] = (unsigned)(rb * 128 + (((ph * 4 + quad) ^ (rb & 7)) * 16));
    }
  }
  const unsigned Au = lds_addr(SM);

  f32x4 acc[2][6] = {};

  STAGE(0, 0);
  VMCNT0;
  ASM_BAR;

  int cur = 0;
  for (int t = 0; t < 32; ++t) {
    int k1 = (t + 1) << 6;
    if (k1 > 2048 - 64) k1 = 2048 - 64;  // last iter: redundant stage into dead slot
    STAGE(cur ^ 1, k1);

    const unsigned aoB = Au + cur * 8192;
    const unsigned atB = Au + 16384 + cur * 8192;
    const unsigned bB  = Au + 32768 + cur * 24576;
    bf16x8 a0o[2], a1o[2], a0t[2], a1t[2], b0[6], b1[6];
#pragma unroll
    for (int i = 0; i < 2; ++i) {
      a0o[i] = ds_read128(aoB + aoff[0][i]);
      a1o[i] = ds_read128(aoB + aoff[1][i]);
    }
    if (wn) {  // wave-uniform: only wn=1 needs the Ht operand
#pragma unroll
      for (int i = 0; i < 2; ++i) {
        a0t[i] = ds_read128(atB + aoff[0][i]);
        a1t[i] = ds_read128(atB + aoff[1][i]);
      }
    }
#pragma unroll
    for (int i = 0; i < 6; ++i) {
      b0[i] = ds_read128(bB + boff[0][i]);
      b1[i] = ds_read128(bB + boff[1][i]);
    }
    LGKM0;
    SCHED0;
    if (!wn) {  // FIX: copy only after the reads have retired (rule #18)
#pragma unroll
      for (int i = 0; i < 2; ++i) { a0t[i] = a0o[i]; a1t[i] = a1o[i]; }
    }
    __builtin_amdgcn_s_setprio(1);
#pragma unroll
    for (int tm = 0; tm < 2; ++tm)
#pragma unroll
      for (int tb = 0; tb < 6; ++tb)
        acc[tm][tb] = __builtin_amdgcn_mfma_f32_16x16x32_bf16(
            tb >= 3 ? a0t[tm] : a0o[tm], b0[tb], acc[tm][tb], 0, 0, 0);
#pragma unroll
    for (int tm = 0; tm < 2; ++tm)
#pragma unroll
      for (int tb = 0; tb < 6; ++tb)
        acc[tm][tb] = __builtin_amdgcn_mfma_f32_16x16x32_bf16(
            tb >= 3 ? a1t[tm] : a1o[tm], b1[tb], acc[tm][tb], 0, 0, 0);
    __builtin_amdgcn_s_setprio(0);
    SCHED0;

    VMCNT0;
    ASM_BAR;
    cur ^= 1;
  }
  // (wn=0: a_t aliases a_o, so "tb>=3 ? a_t : a_o" uses Ho for all 6 omega
  //  subtiles; wn=1: subtiles 6..8 use Ho, 9..11 (tb 3..5) use Ht.)

  // omega subtiles -> Cl (transpose for expm); transl subtiles -> direct.
#pragma unroll
  for (int tm = 0; tm < 2; ++tm) {
#pragma unroll
    for (int tb = 0; tb < 6; ++tb) {
      int st = wn * 6 + tb;
      int s0 = wm * 32 + tm * 16 + quad * 4;
      if (st < 9) {
        int d = st * 16 + l16;
        *(f32x4*)&Cl[d * 68 + s0] = acc[tm][tb];
      } else {
        int n = yt * 48 + (st - 9) * 16 + l16;   // transl row 0..383
        int row0 = mbase + s0;
        int j = n / 3, c2 = n % 3;
        *(f32x4*)&transl[(size_t)n * 2048 + row0] = acc[tm][tb];
        *(f32x4*)&transf[(size_t)(12 * j + 9 + c2) * 2048 + row0] = acc[tm][tb];
      }
    }
  }
  __syncthreads();

  const int jbase = yt * 16;
  const int k = mbase + lane;
#pragma unroll 1
  for (int pp = 0; pp < 4; ++pp) {
    int pl = wave * 4 + pp;  // local part 0..15
    int j = jbase + pl;
    float a[9];
#pragma unroll
    for (int i = 0; i < 9; ++i) a[i] = Cl[(pl * 9 + i) * 68 + lane];
#pragma unroll
    for (int i = 0; i < 9; ++i) omega[(size_t)(9 * j + i) * 2048 + k] = a[i];
    float E[9];
    expm3(a, E);
#pragma unroll
    for (int i = 0; i < 9; ++i) {
      rot[(size_t)(9 * j + i) * 2048 + k] = E[i];
      transf[(size_t)(12 * j + i) * 2048 + k] = E[i];
    }
  }
}

// ---------------------------------------------------------------------------
extern "C" void kernel_launch(void* const* d_in, const int* in_sizes, int n_in,
                              void* d_out, int out_size, void* d_ws, size_t ws_size,
                              hipStream_t stream) {
  const float* x   = (const float*)d_in[0];
  const float* Wo0 = (const float*)d_in[1];
  const float* Wo1 = (const float*)d_in[2];
  const float* Wo2 = (const float*)d_in[3];
  const float* Wo3 = (const float*)d_in[4];
  const float* Wt0 = (const float*)d_in[5];
  const float* Wt1 = (const float*)d_in[6];
  const float* Wt2 = (const float*)d_in[7];
  const float* Wt3 = (const float*)d_in[8];

  unsigned short* wb   = (unsigned short*)d_ws;
  unsigned short* wo0b = wb + 0;
  unsigned short* wo1b = wb + 262144;
  unsigned short* wo2b = wb + 4456448;
  unsigned short* wo3b = wb + 8650752;
  unsigned short* wt0b = wb + 11010048;
  unsigned short* wt1b = wb + 11272192;
  unsigned short* wt2b = wb + 15466496;
  unsigned short* wt3b = wb + 19660800;
  unsigned short* Xt   = wb + 20447232;  // 2048 x 128
  unsigned short* HoA  = Xt + 262144;    // 2048 x 2048 bf16 each
  unsigned short* HoB  = HoA + 4194304;
  unsigned short* HtA  = HoB + 4194304;
  unsigned short* HtB  = HtA + 4194304;
  // total ws use ~108 MB

  prep_k<<<10240, 256, 0, stream>>>(x, Wo0, Wo1, Wo2, Wo3, Wt0, Wt1, Wt2, Wt3, wb, Xt);

  // L0: K=128 -> single K-iteration (proven 2-barrier kernel)
  gemm_tn<1><<<512, 256, 0, stream>>>(Xt, wo0b, HoA, 16, 2048,
                                      Xt, wt0b, HtA, 2048, 128);
  // L1/L2: v4 — dbuf-pipelined 128x128, 2 WGs/CU
  gemm_db128<<<512, 256, 0, stream>>>(HoA, wo1b, HoB, HtA, wt1b, HtB, 2048);
  gemm_db128<<<512, 256, 0, stream>>>(HoB, wo2b, HoA, HtB, wt2b, HtA, 2048);
  // L3 + expm + all outputs: uniform 256-WG merged kernel (1 WG/CU)
  gemm_l3u<<<dim3(32, 8), 256, 0, stream>>>(HoA, wo3b, HtA, wt3b, (float*)d_out);
}

// Round 9
// 234.707 us; speedup vs baseline: 1.0114x; 1.0114x over previous
//
#include <hip/hip_runtime.h>
#include <stdint.h>

// LATENT=128, HIDDEN=2048, N_PARTS=128, K=2048
// outputs: omega(1152,2048) transf(1536,2048) rot(1152,2048) transl(384,2048)

typedef short bf16x8 __attribute__((ext_vector_type(8)));
typedef float f32x4 __attribute__((ext_vector_type(4)));

__device__ __forceinline__ unsigned short f2bf(float f) {
  unsigned int x = __float_as_uint(f);
  unsigned int r = (x + 0x7fffu + ((x >> 16) & 1u)) >> 16;
  return (unsigned short)r;
}

__device__ __forceinline__ void gld_lds16(const void* g, void* l) {
  __builtin_amdgcn_global_load_lds(
      (__attribute__((address_space(1))) void*)(g),
      (__attribute__((address_space(3))) void*)(l),
      16, 0, 0);
}

// LDS byte-offset of a generic pointer into __shared__ (AS3 ptrs are 32-bit).
__device__ __forceinline__ unsigned lds_addr(const void* p) {
  return (unsigned)(uintptr_t)(__attribute__((address_space(3))) const void*)p;
}

// Opaque ds_read_b128: no compiler alias tracking vs LDS-DMA, so no
// auto-inserted vmcnt(0) drains. Consumers MUST be fenced with
// lgkmcnt(0)+sched_barrier(0) (rule #18) — INCLUDING plain register copies
// of the result (round-7 lesson).
__device__ __forceinline__ bf16x8 ds_read128(unsigned a) {
  bf16x8 r;
  asm volatile("ds_read_b128 %0, %1" : "=v"(r) : "v"(a));
  return r;
}

#define ASM_BAR asm volatile("s_barrier" ::: "memory")
#define LGKM0   asm volatile("s_waitcnt lgkmcnt(0)" ::: "memory")
#define VMCNT0  asm volatile("s_waitcnt vmcnt(0)" ::: "memory")
#define SCHED0  __builtin_amdgcn_sched_barrier(0)

// ---------------------------------------------------------------------------
// Prep: blocks 0..9983 cast all 8 weights fp32->bf16 (8 elems/thread, 16 B
// stores); blocks 9984..10239 transpose+cast x (128x2048) -> Xt (2048x128).
__global__ void prep_k(const float* __restrict__ x,
                       const float* __restrict__ wo0, const float* __restrict__ wo1,
                       const float* __restrict__ wo2, const float* __restrict__ wo3,
                       const float* __restrict__ wt0, const float* __restrict__ wt1,
                       const float* __restrict__ wt2, const float* __restrict__ wt3,
                       unsigned short* __restrict__ dst, unsigned short* __restrict__ xt) {
  __shared__ float tile[32][33];
  const int b = blockIdx.x;
  const int tid = threadIdx.x;
  if (b >= 9984) {
    const int r = b - 9984;
    const int bx = r & 63, by = r >> 6;
    const int tx = tid & 31, ty = tid >> 5;
#pragma unroll
    for (int i = 0; i < 32; i += 8)
      tile[ty + i][tx] = x[(size_t)(by * 32 + ty + i) * 2048 + bx * 32 + tx];
    __syncthreads();
#pragma unroll
    for (int i = 0; i < 32; i += 8)
      xt[(size_t)(bx * 32 + ty + i) * 128 + by * 32 + tx] = f2bf(tile[tx][ty + i]);
    return;
  }
  int idx = (b * 256 + tid) * 8;
  if (idx >= 20447232) return;
  const float* src;
  int off;
  if (idx < 8650752) {
    if (idx < 262144)       { src = wo0; off = idx; }
    else if (idx < 4456448) { src = wo1; off = idx - 262144; }
    else                    { src = wo2; off = idx - 4456448; }
  } else {
    if (idx < 11010048)      { src = wo3; off = idx - 8650752; }
    else if (idx < 11272192) { src = wt0; off = idx - 11010048; }
    else if (idx < 15466496) { src = wt1; off = idx - 11272192; }
    else if (idx < 19660800) { src = wt2; off = idx - 15466496; }
    else                     { src = wt3; off = idx - 19660800; }
  }
  float4 a = *(const float4*)(src + off);
  float4 c = *(const float4*)(src + off + 4);
  uint4 o;
  o.x = (unsigned)f2bf(a.x) | ((unsigned)f2bf(a.y) << 16);
  o.y = (unsigned)f2bf(a.z) | ((unsigned)f2bf(a.w) << 16);
  o.z = (unsigned)f2bf(c.x) | ((unsigned)f2bf(c.y) << 16);
  o.w = (unsigned)f2bf(c.z) | ((unsigned)f2bf(c.w) << 16);
  *(uint4*)(dst + idx) = o;
}

// ---------------------------------------------------------------------------
// Proven 128x128-tile TN GEMM (2-barrier structure) — used for L0.
template <int SWZ>
__global__ __launch_bounds__(256, 2) void gemm_tn(
    const unsigned short* __restrict__ A0, const unsigned short* __restrict__ B0,
    unsigned short* __restrict__ C0, int n0tiles, int ldc0,
    const unsigned short* __restrict__ A1, const unsigned short* __restrict__ B1,
    unsigned short* __restrict__ C1, int ldc1, int K) {
  __shared__ alignas(16) unsigned short Asl[128 * 128];
  __shared__ alignas(16) unsigned short Bsl[128 * 128];

  int mt, yt;
  if (SWZ) {
    int id = blockIdx.x;
    int xcd = id & 7, s = id >> 3;
    mt = ((xcd & 1) << 3) + (s & 7);
    yt = ((xcd >> 1) << 3) + (s >> 3);
  } else {
    mt = blockIdx.x;
    yt = blockIdx.y;
  }

  const unsigned short* A;
  const unsigned short* B;
  unsigned short* C;
  int ldc;
  if (yt < n0tiles) { A = A0; B = B0; C = C0; ldc = ldc0; }
  else { A = A1; B = B1; C = C1; ldc = ldc1; yt -= n0tiles; }

  const unsigned short* Ab = A + (size_t)mt * 128 * K;
  const unsigned short* Bb = B + (size_t)yt * 128 * K;

  const int tid = threadIdx.x;
  const int wave = tid >> 6, lane = tid & 63;
  const int mw = (wave >> 1) * 64, nw = (wave & 1) * 64;
  const int l16 = lane & 15, quad = lane >> 4;

  f32x4 acc[4][4] = {};

  for (int k0 = 0; k0 < K; k0 += 128) {
#pragma unroll
    for (int i = 0; i < 8; ++i) {
      int c = i * 256 + tid;
      int row = c >> 4;
      int l = (c & 15) ^ (row & 15);
      gld_lds16(Ab + (size_t)row * K + k0 + l * 8, &Asl[c * 8]);
      gld_lds16(Bb + (size_t)row * K + k0 + l * 8, &Bsl[c * 8]);
    }
    __syncthreads();

#pragma unroll
    for (int h = 0; h < 4; ++h) {
      bf16x8 af[4], bfr[4];
#pragma unroll
      for (int t = 0; t < 4; ++t) {
        int row = mw + t * 16 + l16;
        int p = (h * 4 + quad) ^ (row & 15);
        af[t] = *(const bf16x8*)&Asl[row * 128 + p * 8];
      }
#pragma unroll
      for (int t = 0; t < 4; ++t) {
        int row = nw + t * 16 + l16;
        int p = (h * 4 + quad) ^ (row & 15);
        bfr[t] = *(const bf16x8*)&Bsl[row * 128 + p * 8];
      }
#pragma unroll
      for (int tm = 0; tm < 4; ++tm)
#pragma unroll
        for (int tn = 0; tn < 4; ++tn)
          acc[tm][tn] = __builtin_amdgcn_mfma_f32_16x16x32_bf16(af[tm], bfr[tn], acc[tm][tn], 0, 0, 0);
    }
    __syncthreads();
  }

  const int mbase = mt * 128 + mw;
  const int nbase = yt * 128 + nw;
#pragma unroll
  for (int tm = 0; tm < 4; ++tm) {
#pragma unroll
    for (int tn = 0; tn < 4; ++tn) {
      int col = nbase + tn * 16 + l16;
      int row0 = mbase + tm * 16 + quad * 4;
#pragma unroll
      for (int r = 0; r < 4; ++r) {
        float v = fmaxf(acc[tm][tn][r], 0.0f);
        C[(size_t)(row0 + r) * ldc + col] = f2bf(v);
      }
    }
  }
}

// ---------------------------------------------------------------------------
// v4: 128x128 tile, BK=64, 4 waves, double-buffered 64 KB LDS -> 2 WGs/CU,
// 512 WGs. Round-3-verified wait protocol (no counted vmcnt):
//   STAGE(next tile) -> 16 asm ds_read_b128(cur) -> lgkmcnt(0)+sched_barrier
//   -> 32-MFMA setprio cluster -> vmcnt(0) -> s_barrier.
__global__ __launch_bounds__(256, 2) void gemm_db128(
    const unsigned short* __restrict__ A0, const unsigned short* __restrict__ B0,
    unsigned short* __restrict__ C0,
    const unsigned short* __restrict__ A1, const unsigned short* __restrict__ B1,
    unsigned short* __restrict__ C1, int K) {
  __shared__ alignas(16) unsigned short SM[2 * 16384];  // slot: A[0,8192) B[8192,16384) shorts

  const int id = blockIdx.x;          // 512 WGs
  const int xcd = id & 7, s = id >> 3;          // s in [0,64)
  const int mt = s & 15;                        // 16 M-tiles of 128 samples
  const int ntt = xcd * 4 + (s >> 4);           // 32 N-tiles of 128; XCD owns 4 -> B L2-resident

  const unsigned short* A;
  const unsigned short* B;
  unsigned short* C;
  int ntl;
  if (ntt < 16) { A = A0; B = B0; C = C0; ntl = ntt; }
  else          { A = A1; B = B1; C = C1; ntl = ntt - 16; }

  const unsigned short* Ab = A + (size_t)mt * 128 * K;
  const unsigned short* Bb = B + (size_t)ntl * 128 * K;

  const int tid = threadIdx.x;
  const int wave = tid >> 6, lane = tid & 63;
  const int mw = (wave >> 1) * 64, nw = (wave & 1) * 64;
  const int l16 = lane & 15, quad = lane >> 4;

  // Staging precompute: 4 A-loads + 4 B-loads per thread per tile.
  const unsigned short* gA[4];
  const unsigned short* gB[4];
  int dAo[4], dBo[4];
#pragma unroll
  for (int i = 0; i < 4; ++i) {
    int c = i * 256 + tid;            // 0..1023: 128 rows x 8 chunks
    int row = c >> 3, pc = c & 7, l = pc ^ (row & 7);
    gA[i] = Ab + (size_t)row * K + l * 8;
    dAo[i] = c * 8;
    gB[i] = Bb + (size_t)row * K + l * 8;
    dBo[i] = 8192 + c * 8;
  }

  // Fragment read byte-offsets within a slot, k-sub phase 0/1.
  unsigned aoff[2][4], boff[2][4];
#pragma unroll
  for (int ph = 0; ph < 2; ++ph)
#pragma unroll
    for (int i = 0; i < 4; ++i) {
      int ra = mw + i * 16 + l16;
      aoff[ph][i] = (unsigned)(ra * 128 + (((ph * 4 + quad) ^ (ra & 7)) * 16));
      int rb = nw + i * 16 + l16;
      boff[ph][i] = (unsigned)(16384 + rb * 128 + (((ph * 4 + quad) ^ (rb & 7)) * 16));
    }
  const unsigned Au = lds_addr(SM);   // slot s at Au + s*32768 bytes

  f32x4 acc[4][4] = {};
  const int NT = K >> 6;              // 32 K-tiles

  auto STAGE = [&](int slot, int k1) {
    const int so = slot * 16384;      // shorts
#pragma unroll
    for (int i = 0; i < 4; ++i) gld_lds16(gA[i] + k1, SM + so + dAo[i]);
#pragma unroll
    for (int i = 0; i < 4; ++i) gld_lds16(gB[i] + k1, SM + so + dBo[i]);
  };

  // Prologue: tile 0 staged and drained.
  STAGE(0, 0);
  VMCNT0;
  ASM_BAR;

  int cur = 0;
  for (int t = 0; t < NT; ++t) {
    int k1 = (t + 1) << 6;
    if (k1 > K - 64) k1 = K - 64;     // last iter: redundant stage into dead slot
    STAGE(cur ^ 1, k1);               // 8 loads; waited at end of THIS iter

    const unsigned base = Au + cur * 32768;
    bf16x8 a0[4], b0[4], a1[4], b1[4];
#pragma unroll
    for (int i = 0; i < 4; ++i) a0[i] = ds_read128(base + aoff[0][i]);
#pragma unroll
    for (int i = 0; i < 4; ++i) b0[i] = ds_read128(base + boff[0][i]);
#pragma unroll
    for (int i = 0; i < 4; ++i) a1[i] = ds_read128(base + aoff[1][i]);
#pragma unroll
    for (int i = 0; i < 4; ++i) b1[i] = ds_read128(base + boff[1][i]);
    LGKM0;
    SCHED0;
    __builtin_amdgcn_s_setprio(1);
#pragma unroll
    for (int tm = 0; tm < 4; ++tm)
#pragma unroll
      for (int tn = 0; tn < 4; ++tn)
        acc[tm][tn] = __builtin_amdgcn_mfma_f32_16x16x32_bf16(a0[tm], b0[tn], acc[tm][tn], 0, 0, 0);
#pragma unroll
    for (int tm = 0; tm < 4; ++tm)
#pragma unroll
      for (int tn = 0; tn < 4; ++tn)
        acc[tm][tn] = __builtin_amdgcn_mfma_f32_16x16x32_bf16(a1[tm], b1[tn], acc[tm][tn], 0, 0, 0);
    __builtin_amdgcn_s_setprio(0);
    SCHED0;

    // ---- tile boundary: next tile landed (own stage), slot cur released ----
    VMCNT0;
    ASM_BAR;
    cur ^= 1;
  }

  const int mbase = mt * 128 + mw;
  const int nbase = ntl * 128 + nw;
#pragma unroll
  for (int tm = 0; tm < 4; ++tm) {
#pragma unroll
    for (int tn = 0; tn < 4; ++tn) {
      int col = nbase + tn * 16 + l16;
      int row0 = mbase + tm * 16 + quad * 4;
#pragma unroll
      for (int r = 0; r < 4; ++r) {
        float v = fmaxf(acc[tm][tn][r], 0.0f);
        C[(size_t)(row0 + r) * 2048 + col] = f2bf(v);
      }
    }
  }
}

// ---------------------------------------------------------------------------
// L3 GEMM, unfused: 64x96 tile -> 32 x 16 = 512 WGs, 40 KB LDS -> 2 WGs/CU,
// perfectly balanced (the co-residency regime where the v4 protocol measures
// ~950 TF; cross-round data shows a solo WG pays ~1500 cyc/tile un-hideable
// stall — the reason all fused gemm_l3 variants pinned at 40 us).
// nt<12: chain omega (B=Wo3), fp32 f32x4 stores direct to omega[dim][sample]
// (acc r=0..3 = 4 consecutive samples = contiguous). nt>=12: transl chain
// (B=Wt3), stores transl + transf rows 9..11. No relu (final layer).
// K-loop protocol byte-identical to gemm_db128 (parameter-only change).
__global__ __launch_bounds__(256, 2) void gemm_l3s(
    const unsigned short* __restrict__ Ho, const unsigned short* __restrict__ W9,
    const unsigned short* __restrict__ Ht, const unsigned short* __restrict__ W3,
    float* __restrict__ out) {
  __shared__ alignas(16) unsigned short SM[2 * 4096 + 2 * 6144];  // 40960 B

  const int id = blockIdx.x;    // 512 WGs
  const int mt = id & 31;       // 32 M-tiles of 64 samples
  const int nt = id >> 5;       // 16 N-tiles of 96 dims (12 omega + 4 transl)

  float* omega  = out;
  float* transf = out + (size_t)1152 * 2048;
  float* transl = out + (size_t)(1152 + 1536 + 1152) * 2048;

  const int chain1 = (nt >= 12);
  const unsigned short* A;
  const unsigned short* B;
  if (!chain1) { A = Ho; B = W9 + (size_t)nt * 96 * 2048; }
  else         { A = Ht; B = W3 + (size_t)(nt - 12) * 96 * 2048; }
  const unsigned short* Ab = A + (size_t)mt * 64 * 2048;

  const int tid = threadIdx.x;
  const int wave = tid >> 6, lane = tid & 63;
  const int mw = (wave >> 1) * 32, nw = (wave & 1) * 48;  // 2M x 2N
  const int l16 = lane & 15, quad = lane >> 4;

  // Staging: A 64 rows x 8 chunks = 512 (2/thread); B 96 x 8 = 768 (3/thread).
  const unsigned short* gA[2];
  int dA[2];
#pragma unroll
  for (int i = 0; i < 2; ++i) {
    int c = i * 256 + tid, row = c >> 3, pc = c & 7, l = pc ^ (row & 7);
    gA[i] = Ab + (size_t)row * 2048 + l * 8;
    dA[i] = c * 8;
  }
  const unsigned short* gB[3];
  int dB[3];
#pragma unroll
  for (int i = 0; i < 3; ++i) {
    int c = i * 256 + tid, row = c >> 3, pc = c & 7, l = pc ^ (row & 7);
    gB[i] = B + (size_t)row * 2048 + l * 8;
    dB[i] = c * 8;
  }

  auto STAGE = [&](int s, int k1) {
    const int sa = s * 4096, sb = 8192 + s * 6144;  // shorts
#pragma unroll
    for (int i = 0; i < 2; ++i) gld_lds16(gA[i] + k1, SM + sa + dA[i]);
#pragma unroll
    for (int i = 0; i < 3; ++i) gld_lds16(gB[i] + k1, SM + sb + dB[i]);
  };

  // Fragment byte-offsets (relative to slot region start).
  unsigned aoff[2][2], boff[2][3];
#pragma unroll
  for (int ph = 0; ph < 2; ++ph) {
#pragma unroll
    for (int tm = 0; tm < 2; ++tm) {
      int ra = mw + tm * 16 + l16;
      aoff[ph][tm] = (unsigned)(ra * 128 + (((ph * 4 + quad) ^ (ra & 7)) * 16));
    }
#pragma unroll
    for (int tn = 0; tn < 3; ++tn) {
      int rb = nw + tn * 16 + l16;
      boff[ph][tn] = (unsigned)(rb * 128 + (((ph * 4 + quad) ^ (rb & 7)) * 16));
    }
  }
  const unsigned Au = lds_addr(SM);

  f32x4 acc[2][3] = {};

  STAGE(0, 0);
  VMCNT0;
  ASM_BAR;

  int cur = 0;
  for (int t = 0; t < 32; ++t) {
    int k1 = (t + 1) << 6;
    if (k1 > 2048 - 64) k1 = 2048 - 64;  // last iter: redundant stage into dead slot
    STAGE(cur ^ 1, k1);

    const unsigned aB = Au + cur * 8192;
    const unsigned bB = Au + 16384 + cur * 12288;
    bf16x8 a0[2], b0[3], a1[2], b1[3];
#pragma unroll
    for (int i = 0; i < 2; ++i) a0[i] = ds_read128(aB + aoff[0][i]);
#pragma unroll
    for (int i = 0; i < 3; ++i) b0[i] = ds_read128(bB + boff[0][i]);
#pragma unroll
    for (int i = 0; i < 2; ++i) a1[i] = ds_read128(aB + aoff[1][i]);
#pragma unroll
    for (int i = 0; i < 3; ++i) b1[i] = ds_read128(bB + boff[1][i]);
    LGKM0;
    SCHED0;
    __builtin_amdgcn_s_setprio(1);
#pragma unroll
    for (int tm = 0; tm < 2; ++tm)
#pragma unroll
      for (int tn = 0; tn < 3; ++tn)
        acc[tm][tn] = __builtin_amdgcn_mfma_f32_16x16x32_bf16(a0[tm], b0[tn], acc[tm][tn], 0, 0, 0);
#pragma unroll
    for (int tm = 0; tm < 2; ++tm)
#pragma unroll
      for (int tn = 0; tn < 3; ++tn)
        acc[tm][tn] = __builtin_amdgcn_mfma_f32_16x16x32_bf16(a1[tm], b1[tn], acc[tm][tn], 0, 0, 0);
    __builtin_amdgcn_s_setprio(0);
    SCHED0;

    VMCNT0;
    ASM_BAR;
    cur ^= 1;
  }

  const int mbase = mt * 64 + mw;
#pragma unroll
  for (int tm = 0; tm < 2; ++tm) {
#pragma unroll
    for (int tn = 0; tn < 3; ++tn) {
      int row0 = mbase + tm * 16 + quad * 4;      // sample (mult of 4 -> aligned)
      if (!chain1) {
        int col = nt * 96 + nw + tn * 16 + l16;   // omega dim 0..1151
        *(f32x4*)&omega[(size_t)col * 2048 + row0] = acc[tm][tn];
      } else {
        int n = (nt - 12) * 96 + nw + tn * 16 + l16;  // transl row 0..383
        int j = n / 3, c2 = n % 3;
        *(f32x4*)&transl[(size_t)n * 2048 + row0] = acc[tm][tn];
        *(f32x4*)&transf[(size_t)(12 * j + 9 + c2) * 2048 + row0] = acc[tm][tn];
      }
    }
  }
}

// ---------------------------------------------------------------------------
__device__ __forceinline__ void mm3(const float* a, const float* b, float* c) {
#pragma unroll
  for (int r = 0; r < 3; ++r)
#pragma unroll
    for (int cc = 0; cc < 3; ++cc)
      c[r * 3 + cc] = a[r * 3 + 0] * b[0 + cc] + a[r * 3 + 1] * b[3 + cc] + a[r * 3 + 2] * b[6 + cc];
}

__device__ __forceinline__ void expm3(const float* a, float* E) {
  // scaling-and-squaring + order-12 Taylor (scaled ||A||_1 <= 0.25)
  float n1 = 0.f;
#pragma unroll
  for (int c = 0; c < 3; ++c) {
    float s = fabsf(a[c]) + fabsf(a[3 + c]) + fabsf(a[6 + c]);
    n1 = fmaxf(n1, s);
  }
  int s = 0;
  if (n1 > 0.25f) {
    s = (int)ceilf(log2f(n1 * 4.0f));
    if (s < 0) s = 0;
  }
  const float scl = exp2f((float)(-s));
  float As[9];
#pragma unroll
  for (int i = 0; i < 9; ++i) As[i] = a[i] * scl;
  float T[9] = {1, 0, 0, 0, 1, 0, 0, 0, 1};
#pragma unroll
  for (int i = 0; i < 9; ++i) E[i] = T[i];
#pragma unroll
  for (int t = 1; t <= 12; ++t) {
    float Tn[9];
    mm3(T, As, Tn);
    const float inv = 1.0f / (float)t;
#pragma unroll
    for (int i = 0; i < 9; ++i) { T[i] = Tn[i] * inv; E[i] += T[i]; }
  }
  for (int q = 0; q < s; ++q) {
    float Tn[9];
    mm3(E, E, Tn);
#pragma unroll
    for (int i = 0; i < 9; ++i) E[i] = Tn[i];
  }
}

// ---------------------------------------------------------------------------
// expm epilogue kernel: one (part j, sample k) per thread. 1024 WGs x 256 ->
// 16 waves/CU, pure VALU + coalesced 1KB row reads/writes. Reads omega
// (written by gemm_l3s), writes rot + transf rows 0..8.
__global__ __launch_bounds__(256) void expm_k(const float* __restrict__ out_ro,
                                              float* __restrict__ outw) {
  const float* omega = out_ro;
  float* transf = outw + (size_t)1152 * 2048;
  float* rot    = outw + (size_t)(1152 + 1536) * 2048;

  const int id = blockIdx.x;            // 1024
  const int j = id >> 3;                // part 0..127
  const int k = ((id & 7) << 8) + threadIdx.x;  // sample 0..2047

  float a[9];
#pragma unroll
  for (int i = 0; i < 9; ++i) a[i] = omega[(size_t)(9 * j + i) * 2048 + k];
  float E[9];
  expm3(a, E);
#pragma unroll
  for (int i = 0; i < 9; ++i) {
    rot[(size_t)(9 * j + i) * 2048 + k] = E[i];
    transf[(size_t)(12 * j + i) * 2048 + k] = E[i];
  }
}

// ---------------------------------------------------------------------------
extern "C" void kernel_launch(void* const* d_in, const int* in_sizes, int n_in,
                              void* d_out, int out_size, void* d_ws, size_t ws_size,
                              hipStream_t stream) {
  const float* x   = (const float*)d_in[0];
  const float* Wo0 = (const float*)d_in[1];
  const float* Wo1 = (const float*)d_in[2];
  const float* Wo2 = (const float*)d_in[3];
  const float* Wo3 = (const float*)d_in[4];
  const float* Wt0 = (const float*)d_in[5];
  const float* Wt1 = (const float*)d_in[6];
  const float* Wt2 = (const float*)d_in[7];
  const float* Wt3 = (const float*)d_in[8];

  unsigned short* wb   = (unsigned short*)d_ws;
  unsigned short* wo0b = wb + 0;
  unsigned short* wo1b = wb + 262144;
  unsigned short* wo2b = wb + 4456448;
  unsigned short* wo3b = wb + 8650752;
  unsigned short* wt0b = wb + 11010048;
  unsigned short* wt1b = wb + 11272192;
  unsigned short* wt2b = wb + 15466496;
  unsigned short* wt3b = wb + 19660800;
  unsigned short* Xt   = wb + 20447232;  // 2048 x 128
  unsigned short* HoA  = Xt + 262144;    // 2048 x 2048 bf16 each
  unsigned short* HoB  = HoA + 4194304;
  unsigned short* HtA  = HoB + 4194304;
  unsigned short* HtB  = HtA + 4194304;
  // total ws use ~108 MB

  prep_k<<<10240, 256, 0, stream>>>(x, Wo0, Wo1, Wo2, Wo3, Wt0, Wt1, Wt2, Wt3, wb, Xt);

  // L0: K=128 -> single K-iteration (proven 2-barrier kernel)
  gemm_tn<1><<<512, 256, 0, stream>>>(Xt, wo0b, HoA, 16, 2048,
                                      Xt, wt0b, HtA, 2048, 128);
  // L1/L2: v4 — dbuf-pipelined 128x128, 2 WGs/CU
  gemm_db128<<<512, 256, 0, stream>>>(HoA, wo1b, HoB, HtA, wt1b, HtB, 2048);
  gemm_db128<<<512, 256, 0, stream>>>(HoB, wo2b, HoA, HtB, wt2b, HtA, 2048);
  // L3: unfused — balanced 512-WG GEMM (omega/transl/transf[9:12)) ...
  gemm_l3s<<<512, 256, 0, stream>>>(HoA, wo3b, HtA, wt3b, (float*)d_out);
  // ... then trivially-parallel expm (rot/transf[0:9))
  expm_k<<<1024, 256, 0, stream>>>((const float*)d_out, (float*)d_out);
}

// Round 10
// 234.002 us; speedup vs baseline: 1.0145x; 1.0030x over previous
//
#include <hip/hip_runtime.h>
#include <stdint.h>

// LATENT=128, HIDDEN=2048, N_PARTS=128, K=2048
// outputs: omega(1152,2048) transf(1536,2048) rot(1152,2048) transl(384,2048)

typedef short bf16x8 __attribute__((ext_vector_type(8)));
typedef float f32x4 __attribute__((ext_vector_type(4)));

__device__ __forceinline__ unsigned short f2bf(float f) {
  unsigned int x = __float_as_uint(f);
  unsigned int r = (x + 0x7fffu + ((x >> 16) & 1u)) >> 16;
  return (unsigned short)r;
}

__device__ __forceinline__ void gld_lds16(const void* g, void* l) {
  __builtin_amdgcn_global_load_lds(
      (__attribute__((address_space(1))) void*)(g),
      (__attribute__((address_space(3))) void*)(l),
      16, 0, 0);
}

// LDS byte-offset of a generic pointer into __shared__ (AS3 ptrs are 32-bit).
__device__ __forceinline__ unsigned lds_addr(const void* p) {
  return (unsigned)(uintptr_t)(__attribute__((address_space(3))) const void*)p;
}

// Opaque ds_read_b128: no compiler alias tracking vs LDS-DMA, so no
// auto-inserted vmcnt(0) drains. Consumers MUST be fenced with
// lgkmcnt(0)+sched_barrier(0) (rule #18) — INCLUDING plain register copies
// of the result (round-7 lesson).
__device__ __forceinline__ bf16x8 ds_read128(unsigned a) {
  bf16x8 r;
  asm volatile("ds_read_b128 %0, %1" : "=v"(r) : "v"(a));
  return r;
}

#define ASM_BAR asm volatile("s_barrier" ::: "memory")
#define LGKM0   asm volatile("s_waitcnt lgkmcnt(0)" ::: "memory")
#define VMCNT0  asm volatile("s_waitcnt vmcnt(0)" ::: "memory")
#define SCHED0  __builtin_amdgcn_sched_barrier(0)

// ---------------------------------------------------------------------------
// Prep: blocks 0..9983 cast all 8 weights fp32->bf16 (8 elems/thread, 16 B
// stores); blocks 9984..10239 transpose+cast x (128x2048) -> Xt (2048x128).
__global__ void prep_k(const float* __restrict__ x,
                       const float* __restrict__ wo0, const float* __restrict__ wo1,
                       const float* __restrict__ wo2, const float* __restrict__ wo3,
                       const float* __restrict__ wt0, const float* __restrict__ wt1,
                       const float* __restrict__ wt2, const float* __restrict__ wt3,
                       unsigned short* __restrict__ dst, unsigned short* __restrict__ xt) {
  __shared__ float tile[32][33];
  const int b = blockIdx.x;
  const int tid = threadIdx.x;
  if (b >= 9984) {
    const int r = b - 9984;
    const int bx = r & 63, by = r >> 6;
    const int tx = tid & 31, ty = tid >> 5;
#pragma unroll
    for (int i = 0; i < 32; i += 8)
      tile[ty + i][tx] = x[(size_t)(by * 32 + ty + i) * 2048 + bx * 32 + tx];
    __syncthreads();
#pragma unroll
    for (int i = 0; i < 32; i += 8)
      xt[(size_t)(bx * 32 + ty + i) * 128 + by * 32 + tx] = f2bf(tile[tx][ty + i]);
    return;
  }
  int idx = (b * 256 + tid) * 8;
  if (idx >= 20447232) return;
  const float* src;
  int off;
  if (idx < 8650752) {
    if (idx < 262144)       { src = wo0; off = idx; }
    else if (idx < 4456448) { src = wo1; off = idx - 262144; }
    else                    { src = wo2; off = idx - 4456448; }
  } else {
    if (idx < 11010048)      { src = wo3; off = idx - 8650752; }
    else if (idx < 11272192) { src = wt0; off = idx - 11010048; }
    else if (idx < 15466496) { src = wt1; off = idx - 11272192; }
    else if (idx < 19660800) { src = wt2; off = idx - 15466496; }
    else                     { src = wt3; off = idx - 19660800; }
  }
  float4 a = *(const float4*)(src + off);
  float4 c = *(const float4*)(src + off + 4);
  uint4 o;
  o.x = (unsigned)f2bf(a.x) | ((unsigned)f2bf(a.y) << 16);
  o.y = (unsigned)f2bf(a.z) | ((unsigned)f2bf(a.w) << 16);
  o.z = (unsigned)f2bf(c.x) | ((unsigned)f2bf(c.y) << 16);
  o.w = (unsigned)f2bf(c.z) | ((unsigned)f2bf(c.w) << 16);
  *(uint4*)(dst + idx) = o;
}

// ---------------------------------------------------------------------------
// v4 (verified rounds 4-9): 128x128 tile, BK=64, 4 waves, double-buffered
// 64 KB LDS -> 2 WGs/CU, 512 WGs. Generic in K (any multiple of 64) — used
// for L0 (K=128, NT=2: tile 1 prefetched under tile 0's MFMA) and L1/L2
// (K=2048). Wait protocol:
//   STAGE(next tile) -> 16 asm ds_read_b128(cur) -> lgkmcnt(0)+sched_barrier
//   -> 32-MFMA setprio cluster -> vmcnt(0) -> s_barrier.
__global__ __launch_bounds__(256, 2) void gemm_db128(
    const unsigned short* __restrict__ A0, const unsigned short* __restrict__ B0,
    unsigned short* __restrict__ C0,
    const unsigned short* __restrict__ A1, const unsigned short* __restrict__ B1,
    unsigned short* __restrict__ C1, int K) {
  __shared__ alignas(16) unsigned short SM[2 * 16384];  // slot: A[0,8192) B[8192,16384) shorts

  const int id = blockIdx.x;          // 512 WGs
  const int xcd = id & 7, s = id >> 3;          // s in [0,64)
  const int mt = s & 15;                        // 16 M-tiles of 128 samples
  const int ntt = xcd * 4 + (s >> 4);           // 32 N-tiles of 128; XCD owns 4 -> B L2-resident

  const unsigned short* A;
  const unsigned short* B;
  unsigned short* C;
  int ntl;
  if (ntt < 16) { A = A0; B = B0; C = C0; ntl = ntt; }
  else          { A = A1; B = B1; C = C1; ntl = ntt - 16; }

  const unsigned short* Ab = A + (size_t)mt * 128 * K;
  const unsigned short* Bb = B + (size_t)ntl * 128 * K;

  const int tid = threadIdx.x;
  const int wave = tid >> 6, lane = tid & 63;
  const int mw = (wave >> 1) * 64, nw = (wave & 1) * 64;
  const int l16 = lane & 15, quad = lane >> 4;

  // Staging precompute: 4 A-loads + 4 B-loads per thread per tile.
  const unsigned short* gA[4];
  const unsigned short* gB[4];
  int dAo[4], dBo[4];
#pragma unroll
  for (int i = 0; i < 4; ++i) {
    int c = i * 256 + tid;            // 0..1023: 128 rows x 8 chunks
    int row = c >> 3, pc = c & 7, l = pc ^ (row & 7);
    gA[i] = Ab + (size_t)row * K + l * 8;
    dAo[i] = c * 8;
    gB[i] = Bb + (size_t)row * K + l * 8;
    dBo[i] = 8192 + c * 8;
  }

  // Fragment read byte-offsets within a slot, k-sub phase 0/1.
  unsigned aoff[2][4], boff[2][4];
#pragma unroll
  for (int ph = 0; ph < 2; ++ph)
#pragma unroll
    for (int i = 0; i < 4; ++i) {
      int ra = mw + i * 16 + l16;
      aoff[ph][i] = (unsigned)(ra * 128 + (((ph * 4 + quad) ^ (ra & 7)) * 16));
      int rb = nw + i * 16 + l16;
      boff[ph][i] = (unsigned)(16384 + rb * 128 + (((ph * 4 + quad) ^ (rb & 7)) * 16));
    }
  const unsigned Au = lds_addr(SM);   // slot s at Au + s*32768 bytes

  f32x4 acc[4][4] = {};
  const int NT = K >> 6;              // K-tiles

  auto STAGE = [&](int slot, int k1) {
    const int so = slot * 16384;      // shorts
#pragma unroll
    for (int i = 0; i < 4; ++i) gld_lds16(gA[i] + k1, SM + so + dAo[i]);
#pragma unroll
    for (int i = 0; i < 4; ++i) gld_lds16(gB[i] + k1, SM + so + dBo[i]);
  };

  // Prologue: tile 0 staged and drained.
  STAGE(0, 0);
  VMCNT0;
  ASM_BAR;

  int cur = 0;
  for (int t = 0; t < NT; ++t) {
    int k1 = (t + 1) << 6;
    if (k1 > K - 64) k1 = K - 64;     // last iter: redundant stage into dead slot
    STAGE(cur ^ 1, k1);               // 8 loads; waited at end of THIS iter

    const unsigned base = Au + cur * 32768;
    bf16x8 a0[4], b0[4], a1[4], b1[4];
#pragma unroll
    for (int i = 0; i < 4; ++i) a0[i] = ds_read128(base + aoff[0][i]);
#pragma unroll
    for (int i = 0; i < 4; ++i) b0[i] = ds_read128(base + boff[0][i]);
#pragma unroll
    for (int i = 0; i < 4; ++i) a1[i] = ds_read128(base + aoff[1][i]);
#pragma unroll
    for (int i = 0; i < 4; ++i) b1[i] = ds_read128(base + boff[1][i]);
    LGKM0;
    SCHED0;
    __builtin_amdgcn_s_setprio(1);
#pragma unroll
    for (int tm = 0; tm < 4; ++tm)
#pragma unroll
      for (int tn = 0; tn < 4; ++tn)
        acc[tm][tn] = __builtin_amdgcn_mfma_f32_16x16x32_bf16(a0[tm], b0[tn], acc[tm][tn], 0, 0, 0);
#pragma unroll
    for (int tm = 0; tm < 4; ++tm)
#pragma unroll
      for (int tn = 0; tn < 4; ++tn)
        acc[tm][tn] = __builtin_amdgcn_mfma_f32_16x16x32_bf16(a1[tm], b1[tn], acc[tm][tn], 0, 0, 0);
    __builtin_amdgcn_s_setprio(0);
    SCHED0;

    // ---- tile boundary: next tile landed (own stage), slot cur released ----
    VMCNT0;
    ASM_BAR;
    cur ^= 1;
  }

  const int mbase = mt * 128 + mw;
  const int nbase = ntl * 128 + nw;
#pragma unroll
  for (int tm = 0; tm < 4; ++tm) {
#pragma unroll
    for (int tn = 0; tn < 4; ++tn) {
      int col = nbase + tn * 16 + l16;
      int row0 = mbase + tm * 16 + quad * 4;
#pragma unroll
      for (int r = 0; r < 4; ++r) {
        float v = fmaxf(acc[tm][tn][r], 0.0f);
        C[(size_t)(row0 + r) * 2048 + col] = f2bf(v);
      }
    }
  }
}

// ---------------------------------------------------------------------------
// L3 GEMM, unfused (verified round 9): 64x96 tile -> 512 WGs, 40 KB LDS ->
// 2 WGs/CU balanced. nt<12: omega chain (B=Wo3), direct f32x4 stores to
// omega[dim][sample]. nt>=12: transl chain (B=Wt3), stores transl +
// transf rows 9..11. No relu (final layer). v4 wait protocol.
__global__ __launch_bounds__(256, 2) void gemm_l3s(
    const unsigned short* __restrict__ Ho, const unsigned short* __restrict__ W9,
    const unsigned short* __restrict__ Ht, const unsigned short* __restrict__ W3,
    float* __restrict__ out) {
  __shared__ alignas(16) unsigned short SM[2 * 4096 + 2 * 6144];  // 40960 B

  const int id = blockIdx.x;    // 512 WGs
  const int mt = id & 31;       // 32 M-tiles of 64 samples
  const int nt = id >> 5;       // 16 N-tiles of 96 dims (12 omega + 4 transl)

  float* omega  = out;
  float* transf = out + (size_t)1152 * 2048;
  float* transl = out + (size_t)(1152 + 1536 + 1152) * 2048;

  const int chain1 = (nt >= 12);
  const unsigned short* A;
  const unsigned short* B;
  if (!chain1) { A = Ho; B = W9 + (size_t)nt * 96 * 2048; }
  else         { A = Ht; B = W3 + (size_t)(nt - 12) * 96 * 2048; }
  const unsigned short* Ab = A + (size_t)mt * 64 * 2048;

  const int tid = threadIdx.x;
  const int wave = tid >> 6, lane = tid & 63;
  const int mw = (wave >> 1) * 32, nw = (wave & 1) * 48;  // 2M x 2N
  const int l16 = lane & 15, quad = lane >> 4;

  // Staging: A 64 rows x 8 chunks = 512 (2/thread); B 96 x 8 = 768 (3/thread).
  const unsigned short* gA[2];
  int dA[2];
#pragma unroll
  for (int i = 0; i < 2; ++i) {
    int c = i * 256 + tid, row = c >> 3, pc = c & 7, l = pc ^ (row & 7);
    gA[i] = Ab + (size_t)row * 2048 + l * 8;
    dA[i] = c * 8;
  }
  const unsigned short* gB[3];
  int dB[3];
#pragma unroll
  for (int i = 0; i < 3; ++i) {
    int c = i * 256 + tid, row = c >> 3, pc = c & 7, l = pc ^ (row & 7);
    gB[i] = B + (size_t)row * 2048 + l * 8;
    dB[i] = c * 8;
  }

  auto STAGE = [&](int s, int k1) {
    const int sa = s * 4096, sb = 8192 + s * 6144;  // shorts
#pragma unroll
    for (int i = 0; i < 2; ++i) gld_lds16(gA[i] + k1, SM + sa + dA[i]);
#pragma unroll
    for (int i = 0; i < 3; ++i) gld_lds16(gB[i] + k1, SM + sb + dB[i]);
  };

  // Fragment byte-offsets (relative to slot region start).
  unsigned aoff[2][2], boff[2][3];
#pragma unroll
  for (int ph = 0; ph < 2; ++ph) {
#pragma unroll
    for (int tm = 0; tm < 2; ++tm) {
      int ra = mw + tm * 16 + l16;
      aoff[ph][tm] = (unsigned)(ra * 128 + (((ph * 4 + quad) ^ (ra & 7)) * 16));
    }
#pragma unroll
    for (int tn = 0; tn < 3; ++tn) {
      int rb = nw + tn * 16 + l16;
      boff[ph][tn] = (unsigned)(rb * 128 + (((ph * 4 + quad) ^ (rb & 7)) * 16));
    }
  }
  const unsigned Au = lds_addr(SM);

  f32x4 acc[2][3] = {};

  STAGE(0, 0);
  VMCNT0;
  ASM_BAR;

  int cur = 0;
  for (int t = 0; t < 32; ++t) {
    int k1 = (t + 1) << 6;
    if (k1 > 2048 - 64) k1 = 2048 - 64;  // last iter: redundant stage into dead slot
    STAGE(cur ^ 1, k1);

    const unsigned aB = Au + cur * 8192;
    const unsigned bB = Au + 16384 + cur * 12288;
    bf16x8 a0[2], b0[3], a1[2], b1[3];
#pragma unroll
    for (int i = 0; i < 2; ++i) a0[i] = ds_read128(aB + aoff[0][i]);
#pragma unroll
    for (int i = 0; i < 3; ++i) b0[i] = ds_read128(bB + boff[0][i]);
#pragma unroll
    for (int i = 0; i < 2; ++i) a1[i] = ds_read128(aB + aoff[1][i]);
#pragma unroll
    for (int i = 0; i < 3; ++i) b1[i] = ds_read128(bB + boff[1][i]);
    LGKM0;
    SCHED0;
    __builtin_amdgcn_s_setprio(1);
#pragma unroll
    for (int tm = 0; tm < 2; ++tm)
#pragma unroll
      for (int tn = 0; tn < 3; ++tn)
        acc[tm][tn] = __builtin_amdgcn_mfma_f32_16x16x32_bf16(a0[tm], b0[tn], acc[tm][tn], 0, 0, 0);
#pragma unroll
    for (int tm = 0; tm < 2; ++tm)
#pragma unroll
      for (int tn = 0; tn < 3; ++tn)
        acc[tm][tn] = __builtin_amdgcn_mfma_f32_16x16x32_bf16(a1[tm], b1[tn], acc[tm][tn], 0, 0, 0);
    __builtin_amdgcn_s_setprio(0);
    SCHED0;

    VMCNT0;
    ASM_BAR;
    cur ^= 1;
  }

  const int mbase = mt * 64 + mw;
#pragma unroll
  for (int tm = 0; tm < 2; ++tm) {
#pragma unroll
    for (int tn = 0; tn < 3; ++tn) {
      int row0 = mbase + tm * 16 + quad * 4;      // sample (mult of 4 -> aligned)
      if (!chain1) {
        int col = nt * 96 + nw + tn * 16 + l16;   // omega dim 0..1151
        *(f32x4*)&omega[(size_t)col * 2048 + row0] = acc[tm][tn];
      } else {
        int n = (nt - 12) * 96 + nw + tn * 16 + l16;  // transl row 0..383
        int j = n / 3, c2 = n % 3;
        *(f32x4*)&transl[(size_t)n * 2048 + row0] = acc[tm][tn];
        *(f32x4*)&transf[(size_t)(12 * j + 9 + c2) * 2048 + row0] = acc[tm][tn];
      }
    }
  }
}

// ---------------------------------------------------------------------------
__device__ __forceinline__ void mm3(const float* a, const float* b, float* c) {
#pragma unroll
  for (int r = 0; r < 3; ++r)
#pragma unroll
    for (int cc = 0; cc < 3; ++cc)
      c[r * 3 + cc] = a[r * 3 + 0] * b[0 + cc] + a[r * 3 + 1] * b[3 + cc] + a[r * 3 + 2] * b[6 + cc];
}

__device__ __forceinline__ void expm3(const float* a, float* E) {
  // scaling-and-squaring + order-12 Taylor (scaled ||A||_1 <= 0.25)
  float n1 = 0.f;
#pragma unroll
  for (int c = 0; c < 3; ++c) {
    float s = fabsf(a[c]) + fabsf(a[3 + c]) + fabsf(a[6 + c]);
    n1 = fmaxf(n1, s);
  }
  int s = 0;
  if (n1 > 0.25f) {
    s = (int)ceilf(log2f(n1 * 4.0f));
    if (s < 0) s = 0;
  }
  const float scl = exp2f((float)(-s));
  float As[9];
#pragma unroll
  for (int i = 0; i < 9; ++i) As[i] = a[i] * scl;
  float T[9] = {1, 0, 0, 0, 1, 0, 0, 0, 1};
#pragma unroll
  for (int i = 0; i < 9; ++i) E[i] = T[i];
#pragma unroll
  for (int t = 1; t <= 12; ++t) {
    float Tn[9];
    mm3(T, As, Tn);
    const float inv = 1.0f / (float)t;
#pragma unroll
    for (int i = 0; i < 9; ++i) { T[i] = Tn[i] * inv; E[i] += T[i]; }
  }
  for (int q = 0; q < s; ++q) {
    float Tn[9];
    mm3(E, E, Tn);
#pragma unroll
    for (int i = 0; i < 9; ++i) E[i] = Tn[i];
  }
}

// ---------------------------------------------------------------------------
// expm epilogue kernel: one (part j, sample k) per thread. 1024 WGs x 256 ->
// 16 waves/CU, pure VALU + coalesced 1KB row reads/writes. Reads omega
// (written by gemm_l3s), writes rot + transf rows 0..8.
__global__ __launch_bounds__(256) void expm_k(const float* __restrict__ out_ro,
                                              float* __restrict__ outw) {
  const float* omega = out_ro;
  float* transf = outw + (size_t)1152 * 2048;
  float* rot    = outw + (size_t)(1152 + 1536) * 2048;

  const int id = blockIdx.x;            // 1024
  const int j = id >> 3;                // part 0..127
  const int k = ((id & 7) << 8) + threadIdx.x;  // sample 0..2047

  float a[9];
#pragma unroll
  for (int i = 0; i < 9; ++i) a[i] = omega[(size_t)(9 * j + i) * 2048 + k];
  float E[9];
  expm3(a, E);
#pragma unroll
  for (int i = 0; i < 9; ++i) {
    rot[(size_t)(9 * j + i) * 2048 + k] = E[i];
    transf[(size_t)(12 * j + i) * 2048 + k] = E[i];
  }
}

// ---------------------------------------------------------------------------
extern "C" void kernel_launch(void* const* d_in, const int* in_sizes, int n_in,
                              void* d_out, int out_size, void* d_ws, size_t ws_size,
                              hipStream_t stream) {
  const float* x   = (const float*)d_in[0];
  const float* Wo0 = (const float*)d_in[1];
  const float* Wo1 = (const float*)d_in[2];
  const float* Wo2 = (const float*)d_in[3];
  const float* Wo3 = (const float*)d_in[4];
  const float* Wt0 = (const float*)d_in[5];
  const float* Wt1 = (const float*)d_in[6];
  const float* Wt2 = (const float*)d_in[7];
  const float* Wt3 = (const float*)d_in[8];

  unsigned short* wb   = (unsigned short*)d_ws;
  unsigned short* wo0b = wb + 0;
  unsigned short* wo1b = wb + 262144;
  unsigned short* wo2b = wb + 4456448;
  unsigned short* wo3b = wb + 8650752;
  unsigned short* wt0b = wb + 11010048;
  unsigned short* wt1b = wb + 11272192;
  unsigned short* wt2b = wb + 15466496;
  unsigned short* wt3b = wb + 19660800;
  unsigned short* Xt   = wb + 20447232;  // 2048 x 128
  unsigned short* HoA  = Xt + 262144;    // 2048 x 2048 bf16 each
  unsigned short* HoB  = HoA + 4194304;
  unsigned short* HtA  = HoB + 4194304;
  unsigned short* HtB  = HtA + 4194304;
  // total ws use ~108 MB

  prep_k<<<10240, 256, 0, stream>>>(x, Wo0, Wo1, Wo2, Wo3, Wt0, Wt1, Wt2, Wt3, wb, Xt);

  // L0: K=128 (NT=2) through the verified pipelined kernel — tile 1
  // prefetched under tile 0's MFMA (replaces the old full-drain gemm_tn).
  gemm_db128<<<512, 256, 0, stream>>>(Xt, wo0b, HoA, Xt, wt0b, HtA, 128);
  // L1/L2: v4 — dbuf-pipelined 128x128, 2 WGs/CU
  gemm_db128<<<512, 256, 0, stream>>>(HoA, wo1b, HoB, HtA, wt1b, HtB, 2048);
  gemm_db128<<<512, 256, 0, stream>>>(HoB, wo2b, HoA, HtB, wt2b, HtA, 2048);
  // L3: unfused — balanced 512-WG GEMM (omega/transl/transf[9:12)) ...
  gemm_l3s<<<512, 256, 0, stream>>>(HoA, wo3b, HtA, wt3b, (float*)d_out);
  // ... then trivially-parallel expm (rot/transf[0:9))
  expm_k<<<1024, 256, 0, stream>>>((const float*)d_out, (float*)d_out);
}